// Round 2
// baseline (2583.836 us; speedup 1.0000x reference)
//
#include <hip/hip_runtime.h>
#include <cstdint>

// FPS: B=8, N=131072, NPOINT=1024.  Exact-index replication of the jax reference.
//
// v2-safe: keeps the HARNESS-PROVEN exchange protocol of the 2036us kernel
// (LDS atomic-max fan-in -> one barrier -> tid0 posts agent-scope slot ->
// all-wave bounded-progress spin on exact round tags, parity double-buffer,
// monotone tags, no resets, 4 KiB workspace) and changes ONLY:
//   * 256 blocks x 512 thr (was 128 x 1024): all 256 CUs work, per-SIMD
//     compute-issue time halves (2 waves/SIMD instead of 4).
//   * batch b = blockIdx&7 -> 32 blocks/batch, still one XCD per batch.
//   * per-thread state as packed f32 pairs (v_pk_add/mul; IEEE-RN identical
//     to scalar, fp contract(off) preserves the jnp rounding order).
//   * fan-in is 8 wave-winners (was 16).
//   * spin: lanes 0..15 poll 2 slots each (32 slots/batch), group16 combine.
// Packed key u64: [t:15][fp32 dist bits:32][(~idx)&0x1FFFF:17] -> unsigned max
// == (round, dist desc, idx asc) == np.argmax first-max tie-break.  Poisoned
// workspace (0x5555...) has tag 0x2AAA > 1023: never matches a live round.

constexpr int kB = 8;
constexpr int kN = 131072;
constexpr int kNpoint = 1024;
constexpr int kBlocksPerBatch = 32;
constexpr int kThreads = 512;
constexpr int kPPT = 8;
constexpr int kPtsPerBlock = kThreads * kPPT;  // 4096

typedef float f32x2 __attribute__((ext_vector_type(2)));

__device__ __forceinline__ uint64_t u64max(uint64_t a, uint64_t b) {
    return a > b ? a : b;
}

// DPP move of a u64 (both halves, same ctrl); invalid source lanes yield 0,
// the identity for our non-negative packed keys.
template <int CTRL>
__device__ __forceinline__ uint64_t dpp_u64(uint64_t v) {
    int lo = __builtin_amdgcn_update_dpp(0, (int)(uint32_t)v, CTRL, 0xF, 0xF, false);
    int hi = __builtin_amdgcn_update_dpp(0, (int)(uint32_t)(v >> 32), CTRL, 0xF, 0xF, false);
    return ((uint64_t)(uint32_t)hi << 32) | (uint32_t)lo;
}

// Full-wave max; result valid in lane 63 (row_shr/row_bcast ladder).
__device__ __forceinline__ uint64_t wave_max_to_lane63(uint64_t v) {
    v = u64max(v, dpp_u64<0x111>(v));  // row_shr:1
    v = u64max(v, dpp_u64<0x112>(v));  // row_shr:2
    v = u64max(v, dpp_u64<0x114>(v));  // row_shr:4
    v = u64max(v, dpp_u64<0x118>(v));  // row_shr:8
    v = u64max(v, dpp_u64<0x142>(v));  // row_bcast:15
    v = u64max(v, dpp_u64<0x143>(v));  // row_bcast:31
    return v;
}

// Max over each aligned group of 16 lanes (butterfly xor1,2,4,8).
__device__ __forceinline__ uint64_t group16_max(uint64_t v) {
    v = u64max(v, dpp_u64<0xB1>(v));   // quad_perm xor1
    v = u64max(v, dpp_u64<0x4E>(v));   // quad_perm xor2
    v = u64max(v, dpp_u64<0x141>(v));  // row_half_mirror
    v = u64max(v, dpp_u64<0x140>(v));  // row_mirror
    return v;
}

__device__ __forceinline__ uint64_t ld_u64_agent(const uint64_t* p) {
    return __hip_atomic_load(p, __ATOMIC_RELAXED, __HIP_MEMORY_SCOPE_AGENT);
}
__device__ __forceinline__ void st_u64_agent(uint64_t* p, uint64_t v) {
    __hip_atomic_store(p, v, __ATOMIC_RELAXED, __HIP_MEMORY_SCOPE_AGENT);
}

__global__ __launch_bounds__(kThreads, 2) void fps_kernel(
        const float* __restrict__ xyz, float* __restrict__ out,
        uint64_t* __restrict__ slots) {
#pragma clang fp contract(off)
    const int b    = blockIdx.x & 7;    // batch: all 32 blocks of a batch on one XCD
    const int blk  = blockIdx.x >> 3;   // block within batch, 0..31
    const int tid  = threadIdx.x;
    const int lane = tid & 63;

    const float* __restrict__ base = xyz + (size_t)b * kN * 3;

    // Register-resident state as packed pairs: element .x is point j=2q,
    // .y is j=2q+1 (ascending index order preserved for the tie-break).
    f32x2 X[4], Y[4], Z[4], MD[4];
#pragma unroll
    for (int q = 0; q < 4; ++q) {
        const int p0 = blk * kPtsPerBlock + (2 * q) * kThreads + tid;
        const int p1 = p0 + kThreads;
        X[q].x = base[3 * p0 + 0]; X[q].y = base[3 * p1 + 0];
        Y[q].x = base[3 * p0 + 1]; Y[q].y = base[3 * p1 + 1];
        Z[q].x = base[3 * p0 + 2]; Z[q].y = base[3 * p1 + 2];
        MD[q].x = __builtin_inff(); MD[q].y = __builtin_inff();
    }

    __shared__ uint64_t lbest[2];
    if (tid == 0) { lbest[0] = 0; lbest[1] = 0; }

    // First sample is always point 0.
    float cx = base[0], cy = base[1], cz = base[2];
    if (blk == 0 && tid == 0) {
        float* o = out + (size_t)b * kNpoint * 3;
        o[0] = cx; o[1] = cy; o[2] = cz;
    }
    __syncthreads();  // lbest init visible

    for (int t = 1; t < kNpoint; ++t) {
        // --- mindist update + per-thread argmax (exact fp32, no contraction) ---
        const f32x2 vcx = {cx, cx}, vcy = {cy, cy}, vcz = {cz, cz};
        float bm = -1.0f;
        int   bj = 0;
#pragma unroll
        for (int q = 0; q < 4; ++q) {
            const f32x2 dx = X[q] - vcx;
            const f32x2 dy = Y[q] - vcy;
            const f32x2 dz = Z[q] - vcz;
            const f32x2 d  = (dx * dx + dy * dy) + dz * dz;  // (xx+yy)+zz, RN
            f32x2 m;
            m.x = fminf(MD[q].x, d.x);
            m.y = fminf(MD[q].y, d.y);
            MD[q] = m;
            // .x is the smaller index -- evaluate first; strict > keeps first max
            const bool g0 = m.x > bm;  bj = g0 ? (2 * q)     : bj;  bm = g0 ? m.x : bm;
            const bool g1 = m.y > bm;  bj = g1 ? (2 * q + 1) : bj;  bm = g1 ? m.y : bm;
        }
        const uint32_t p = (uint32_t)(blk * kPtsPerBlock + bj * kThreads + tid);
        uint64_t pk = ((uint64_t)t << 49) |
                      ((uint64_t)__float_as_uint(bm) << 17) |
                      ((~p) & 0x1FFFFu);

        // --- wave max -> lane 63 -> LDS atomic max (tag-packed, parity dbuf) ---
        pk = wave_max_to_lane63(pk);
        if (lane == 63) {
            __hip_atomic_fetch_max(&lbest[t & 1], pk, __ATOMIC_RELAXED,
                                   __HIP_MEMORY_SCOPE_WORKGROUP);
        }
        __syncthreads();  // the one barrier: block best complete in LDS

        uint64_t* const slotbuf = slots + ((size_t)(t & 1) * kB + b) * kBlocksPerBatch;
        if (tid == 0) {
            // already tagged with t; single-u64 payload -> relaxed suffices
            st_u64_agent(&slotbuf[blk], lbest[t & 1]);
        }

        // --- every wave spins: lanes 0..15 poll 2 slots each (32 slots) ---
        uint64_t v0 = 0, v1 = 0;
        bool need = lane < 16;
        const uint64_t tt = (uint64_t)t;
        while (__any(need)) {
            if (need) {
                const uint64_t a = ld_u64_agent(&slotbuf[lane]);
                const uint64_t c = ld_u64_agent(&slotbuf[lane + 16]);
                if (((a >> 49) == tt) & ((c >> 49) == tt)) {
                    v0 = a; v1 = c; need = false;
                }
            }
        }
        uint64_t got = group16_max(u64max(v0, v1));  // lanes 0-15: batch winner

        // broadcast via scalar regs; winner coords from read-only xyz (L2-hit)
        const uint32_t lo = (uint32_t)got;
        const uint32_t widx = 131071u - (__builtin_amdgcn_readfirstlane((int)lo) & 0x1FFFFu);
        cx = base[3 * (size_t)widx + 0];
        cy = base[3 * (size_t)widx + 1];
        cz = base[3 * (size_t)widx + 2];
        if (blk == 0 && tid == 0) {
            float* o = out + ((size_t)b * kNpoint + t) * 3;
            o[0] = cx; o[1] = cy; o[2] = cz;
        }
    }
}

extern "C" void kernel_launch(void* const* d_in, const int* in_sizes, int n_in,
                              void* d_out, int out_size, void* d_ws, size_t ws_size,
                              hipStream_t stream) {
    const float* xyz = (const float*)d_in[0];
    float* out = (float*)d_out;
    uint64_t* slots = (uint64_t*)d_ws;  // 2 * 8 * 32 u64 = 4 KiB used
    fps_kernel<<<dim3(kB * kBlocksPerBatch), dim3(kThreads), 0, stream>>>(xyz, out, slots);
}

// Round 3
// 2551.361 us; speedup vs baseline: 1.0127x; 1.0127x over previous
//
#include <hip/hip_runtime.h>
#include <cstdint>

// FPS: B=8, N=131072, NPOINT=1024.  Exact-index replication of the jax reference.
//
// v3: single-poller exchange. v2 showed the agent-scope slot exchange is
// CONTENTION-bound: 2048 waves spinning on MALL-serviced loads stretched the
// round to 2.5us. This version keeps v2's compute layout (256 blocks x 512
// thr, packed f32 pairs, 32 blocks/batch pinned per-XCD) and the proven
// protocol (tag-packed keys, parity dbuf, monotone tags, LDS atomic fan-in,
// 4 KiB workspace) but ONLY wave 0 of each block polls:
//   update -> DPP wave max -> LDS atomic max (8 waves) -> barrier A
//   -> tid0 posts tagged key (agent scope)
//   -> wave0 lanes 0..31 poll the 32 batch slots (1 u64/lane/iter);
//      waves 1..7 sleep at barrier B
//   -> wave0 DPP-reduces, lanes 0..2 fetch winner coords (one L2 line),
//      write LDS bc[t&1] (+ out for blk 0)
//   -> barrier B -> all waves read bc.
// Poll traffic drops 8x (256 pollers, 1 load/lane) -> exchange returns to
// latency-bound regime. Poll termination: every block posts BEFORE its wave0
// polls, so all 32 posts/round are unconditionally issued; parity dbuf makes
// cross-round slot reuse race-free (tags monotone; poison tag 0x2AAA never
// matches a live round).
// Packed key u64: [t:15][fp32 dist bits:32][(~idx)&0x1FFFF:17] -> unsigned max
// == (round, dist desc, idx asc) == np.argmax first-max tie-break.

constexpr int kB = 8;
constexpr int kN = 131072;
constexpr int kNpoint = 1024;
constexpr int kBlocksPerBatch = 32;
constexpr int kThreads = 512;
constexpr int kPPT = 8;
constexpr int kPtsPerBlock = kThreads * kPPT;  // 4096

typedef float f32x2 __attribute__((ext_vector_type(2)));

__device__ __forceinline__ uint64_t u64max(uint64_t a, uint64_t b) {
    return a > b ? a : b;
}

// DPP move of a u64 (both halves, same ctrl); invalid source lanes yield 0,
// the identity for our non-negative packed keys.
template <int CTRL>
__device__ __forceinline__ uint64_t dpp_u64(uint64_t v) {
    int lo = __builtin_amdgcn_update_dpp(0, (int)(uint32_t)v, CTRL, 0xF, 0xF, false);
    int hi = __builtin_amdgcn_update_dpp(0, (int)(uint32_t)(v >> 32), CTRL, 0xF, 0xF, false);
    return ((uint64_t)(uint32_t)hi << 32) | (uint32_t)lo;
}

// Full-wave max; result valid in lane 63 (row_shr/row_bcast ladder).
__device__ __forceinline__ uint64_t wave_max_to_lane63(uint64_t v) {
    v = u64max(v, dpp_u64<0x111>(v));  // row_shr:1
    v = u64max(v, dpp_u64<0x112>(v));  // row_shr:2
    v = u64max(v, dpp_u64<0x114>(v));  // row_shr:4
    v = u64max(v, dpp_u64<0x118>(v));  // row_shr:8
    v = u64max(v, dpp_u64<0x142>(v));  // row_bcast:15
    v = u64max(v, dpp_u64<0x143>(v));  // row_bcast:31
    return v;
}

__device__ __forceinline__ uint64_t ld_u64_agent(const uint64_t* p) {
    return __hip_atomic_load(p, __ATOMIC_RELAXED, __HIP_MEMORY_SCOPE_AGENT);
}
__device__ __forceinline__ void st_u64_agent(uint64_t* p, uint64_t v) {
    __hip_atomic_store(p, v, __ATOMIC_RELAXED, __HIP_MEMORY_SCOPE_AGENT);
}

__global__ __launch_bounds__(kThreads, 2) void fps_kernel(
        const float* __restrict__ xyz, float* __restrict__ out,
        uint64_t* __restrict__ slots) {
#pragma clang fp contract(off)
    const int b    = blockIdx.x & 7;    // batch: all 32 blocks of a batch on one XCD
    const int blk  = blockIdx.x >> 3;   // block within batch, 0..31
    const int tid  = threadIdx.x;
    const int lane = tid & 63;
    const int wave = tid >> 6;          // 0..7

    const float* __restrict__ base = xyz + (size_t)b * kN * 3;

    // Register-resident state as packed pairs: element .x is point j=2q,
    // .y is j=2q+1 (ascending index order preserved for the tie-break).
    f32x2 X[4], Y[4], Z[4], MD[4];
#pragma unroll
    for (int q = 0; q < 4; ++q) {
        const int p0 = blk * kPtsPerBlock + (2 * q) * kThreads + tid;
        const int p1 = p0 + kThreads;
        X[q].x = base[3 * p0 + 0]; X[q].y = base[3 * p1 + 0];
        Y[q].x = base[3 * p0 + 1]; Y[q].y = base[3 * p1 + 1];
        Z[q].x = base[3 * p0 + 2]; Z[q].y = base[3 * p1 + 2];
        MD[q].x = __builtin_inff(); MD[q].y = __builtin_inff();
    }

    __shared__ uint64_t lbest[2];
    __shared__ float bc[2][3];
    if (tid == 0) { lbest[0] = 0; lbest[1] = 0; }

    // First sample is always point 0.
    float cx = base[0], cy = base[1], cz = base[2];
    if (blk == 0 && tid == 0) {
        float* o = out + (size_t)b * kNpoint * 3;
        o[0] = cx; o[1] = cy; o[2] = cz;
    }
    __syncthreads();  // lbest init visible

    for (int t = 1; t < kNpoint; ++t) {
        // --- mindist update + per-thread argmax (exact fp32, no contraction) ---
        const f32x2 vcx = {cx, cx}, vcy = {cy, cy}, vcz = {cz, cz};
        float bm = -1.0f;
        int   bj = 0;
#pragma unroll
        for (int q = 0; q < 4; ++q) {
            const f32x2 dx = X[q] - vcx;
            const f32x2 dy = Y[q] - vcy;
            const f32x2 dz = Z[q] - vcz;
            const f32x2 d  = (dx * dx + dy * dy) + dz * dz;  // (xx+yy)+zz, RN
            f32x2 m;
            m.x = fminf(MD[q].x, d.x);
            m.y = fminf(MD[q].y, d.y);
            MD[q] = m;
            // .x is the smaller index -- evaluate first; strict > keeps first max
            const bool g0 = m.x > bm;  bj = g0 ? (2 * q)     : bj;  bm = g0 ? m.x : bm;
            const bool g1 = m.y > bm;  bj = g1 ? (2 * q + 1) : bj;  bm = g1 ? m.y : bm;
        }
        const uint32_t p = (uint32_t)(blk * kPtsPerBlock + bj * kThreads + tid);
        uint64_t pk = ((uint64_t)t << 49) |
                      ((uint64_t)__float_as_uint(bm) << 17) |
                      ((~p) & 0x1FFFFu);

        // --- wave max -> lane 63 -> LDS atomic max (tag-packed, parity dbuf) ---
        pk = wave_max_to_lane63(pk);
        if (lane == 63) {
            __hip_atomic_fetch_max(&lbest[t & 1], pk, __ATOMIC_RELAXED,
                                   __HIP_MEMORY_SCOPE_WORKGROUP);
        }
        __syncthreads();  // barrier A: block best complete in LDS

        uint64_t* const slotbuf = slots + ((size_t)(t & 1) * kB + b) * kBlocksPerBatch;
        if (tid == 0) {
            // already tagged with t; single-u64 payload -> relaxed suffices
            st_u64_agent(&slotbuf[blk], lbest[t & 1]);
        }

        // --- wave 0 polls the 32 slots (1/lane); waves 1..7 sleep at barrier B ---
        if (wave == 0) {
            uint64_t got = 0;
            bool need = lane < kBlocksPerBatch;
            const uint64_t tt = (uint64_t)t;
            while (__any(need)) {
                if (need) {
                    const uint64_t sv = ld_u64_agent(&slotbuf[lane]);
                    if ((sv >> 49) == tt) { got = sv; need = false; }
                }
            }
            const uint64_t wk = wave_max_to_lane63(got);
            const uint32_t wlo = (uint32_t)__builtin_amdgcn_readlane((int)(uint32_t)wk, 63);
            const uint32_t widx = 131071u - (wlo & 0x1FFFFu);  // uniform (scalar)
            if (lane < 3) {
                // one L2-resident line; 3 lanes in parallel
                const float v = base[3 * (size_t)widx + lane];
                bc[t & 1][lane] = v;
                if (blk == 0) out[((size_t)b * kNpoint + t) * 3 + lane] = v;
            }
        }
        __syncthreads();  // barrier B: winner coords in LDS
        cx = bc[t & 1][0];
        cy = bc[t & 1][1];
        cz = bc[t & 1][2];
    }
}

extern "C" void kernel_launch(void* const* d_in, const int* in_sizes, int n_in,
                              void* d_out, int out_size, void* d_ws, size_t ws_size,
                              hipStream_t stream) {
    const float* xyz = (const float*)d_in[0];
    float* out = (float*)d_out;
    uint64_t* slots = (uint64_t*)d_ws;  // 2 * 8 * 32 u64 = 4 KiB used
    fps_kernel<<<dim3(kB * kBlocksPerBatch), dim3(kThreads), 0, stream>>>(xyz, out, slots);
}

// Round 4
// 2085.905 us; speedup vs baseline: 1.2387x; 1.2231x over previous
//
#include <hip/hip_runtime.h>
#include <cstdint>

// FPS: B=8, N=131072, NPOINT=1024.  Exact-index replication of the jax reference.
//
// v4: v0's proven one-barrier protocol (16 blocks/batch, all-wave spin,
// monotone tag-packed keys, parity dbuf, no resets) + v2's packed-pair
// compute + a dual-path exchange:
//   * tid0 posts the block winner TWICE: plain store -> fastbuf (lands in the
//     block's XCD-shared L2; all 16 blocks of a batch sit on one XCD under
//     round-robin dispatch) and agent-scope store -> agentbuf (MALL, the
//     proven v0 path, guaranteed visible on ANY placement).
//   * pollers (lanes 0-15 of every wave) spin on fastbuf via sc0 (SE-scope)
//     loads for kFastIters, then fall back to agent loads. Fallback is
//     unconditional-progress: agent posts are always issued, so no hang.
//   * fastbuf/agentbuf are DISJOINT lines: dirty fast lines in an L2 can be
//     written back to MALL arbitrarily late and must never alias the slots
//     the fallback path trusts.
//   * sticky LDS flag kills the fast phase for the rest of the kernel after
//     one timeout -> pathological placement degrades to v0 perf, not hang.
// Packed key u64: [t:15][fp32 dist bits:32][(~idx)&0x1FFFF:17] -> unsigned max
// == (round, dist desc, idx asc) == np.argmax first-max tie-break.  Poisoned
// workspace (0x5555...) has tag 0x2AAA > 1023: never matches a live round.

constexpr int kB = 8;
constexpr int kN = 131072;
constexpr int kNpoint = 1024;
constexpr int kBlocksPerBatch = 16;
constexpr int kThreads = 1024;
constexpr int kPPT = 8;
constexpr int kPtsPerBlock = kThreads * kPPT;  // 8192
constexpr int kFastIters = 12;

typedef float f32x2 __attribute__((ext_vector_type(2)));

__device__ __forceinline__ uint64_t u64max(uint64_t a, uint64_t b) {
    return a > b ? a : b;
}

// DPP move of a u64 (both halves, same ctrl); invalid source lanes yield 0,
// the identity for our non-negative packed keys.
template <int CTRL>
__device__ __forceinline__ uint64_t dpp_u64(uint64_t v) {
    int lo = __builtin_amdgcn_update_dpp(0, (int)(uint32_t)v, CTRL, 0xF, 0xF, false);
    int hi = __builtin_amdgcn_update_dpp(0, (int)(uint32_t)(v >> 32), CTRL, 0xF, 0xF, false);
    return ((uint64_t)(uint32_t)hi << 32) | (uint32_t)lo;
}

// Full-wave max; result valid in lane 63 (row_shr/row_bcast ladder).
__device__ __forceinline__ uint64_t wave_max_to_lane63(uint64_t v) {
    v = u64max(v, dpp_u64<0x111>(v));  // row_shr:1
    v = u64max(v, dpp_u64<0x112>(v));  // row_shr:2
    v = u64max(v, dpp_u64<0x114>(v));  // row_shr:4
    v = u64max(v, dpp_u64<0x118>(v));  // row_shr:8
    v = u64max(v, dpp_u64<0x142>(v));  // row_bcast:15
    v = u64max(v, dpp_u64<0x143>(v));  // row_bcast:31
    return v;
}

// Max over each aligned group of 16 lanes (butterfly xor1,2,4,8).
__device__ __forceinline__ uint64_t group16_max(uint64_t v) {
    v = u64max(v, dpp_u64<0xB1>(v));   // quad_perm xor1
    v = u64max(v, dpp_u64<0x4E>(v));   // quad_perm xor2
    v = u64max(v, dpp_u64<0x141>(v));  // row_half_mirror
    v = u64max(v, dpp_u64<0x140>(v));  // row_mirror
    return v;
}

__device__ __forceinline__ uint64_t ld_u64_agent(const uint64_t* p) {
    return __hip_atomic_load(p, __ATOMIC_RELAXED, __HIP_MEMORY_SCOPE_AGENT);
}
__device__ __forceinline__ void st_u64_agent(uint64_t* p, uint64_t v) {
    __hip_atomic_store(p, v, __ATOMIC_RELAXED, __HIP_MEMORY_SCOPE_AGENT);
}
// Plain store: vL1 is write-through -> lands in the home XCD's L2.
__device__ __forceinline__ void st_u64_plain(uint64_t* p, uint64_t v) {
    asm volatile("global_store_dwordx2 %0, %1, off" :: "v"(p), "v"(v) : "memory");
}
// SE-scope load (bypass L1, read L2). Load + waitcnt fused in ONE asm so the
// dependent tag check cannot be scheduled before the wait (rule #18).
__device__ __forceinline__ uint64_t ld_u64_l2(const uint64_t* p) {
    uint64_t v;
    asm volatile("global_load_dwordx2 %0, %1, off sc0\n\t"
                 "s_waitcnt vmcnt(0)"
                 : "=v"(v) : "v"(p) : "memory");
    return v;
}

__global__ __launch_bounds__(kThreads, 4) void fps_kernel(
        const float* __restrict__ xyz, float* __restrict__ out,
        uint64_t* __restrict__ ws) {
#pragma clang fp contract(off)
    const int b    = blockIdx.x & 7;    // batch: all 16 blocks of a batch on one XCD
    const int blk  = blockIdx.x >> 3;   // block within batch, 0..15
    const int tid  = threadIdx.x;
    const int lane = tid & 63;

    uint64_t* const fastbuf  = ws;                              // [2][8][16]
    uint64_t* const agentbuf = ws + 2 * kB * kBlocksPerBatch;   // [2][8][16]

    const float* __restrict__ base = xyz + (size_t)b * kN * 3;

    // Register-resident state as packed pairs: .x is point j=2q, .y is j=2q+1
    // (ascending index order preserved for the first-max tie-break).
    f32x2 X[4], Y[4], Z[4], MD[4];
#pragma unroll
    for (int q = 0; q < 4; ++q) {
        const int p0 = blk * kPtsPerBlock + (2 * q) * kThreads + tid;
        const int p1 = p0 + kThreads;
        X[q].x = base[3 * p0 + 0]; X[q].y = base[3 * p1 + 0];
        Y[q].x = base[3 * p0 + 1]; Y[q].y = base[3 * p1 + 1];
        Z[q].x = base[3 * p0 + 2]; Z[q].y = base[3 * p1 + 2];
        MD[q].x = __builtin_inff(); MD[q].y = __builtin_inff();
    }

    __shared__ uint64_t lbest[2];
    __shared__ int fastOK;
    if (tid == 0) { lbest[0] = 0; lbest[1] = 0; fastOK = 1; }

    // First sample is always point 0.
    float cx = base[0], cy = base[1], cz = base[2];
    if (blk == 0 && tid == 0) {
        float* o = out + (size_t)b * kNpoint * 3;
        o[0] = cx; o[1] = cy; o[2] = cz;
    }
    __syncthreads();  // lbest/fastOK init visible

    for (int t = 1; t < kNpoint; ++t) {
        // --- mindist update + per-thread argmax (exact fp32, no contraction) ---
        const f32x2 vcx = {cx, cx}, vcy = {cy, cy}, vcz = {cz, cz};
        float bm = -1.0f;
        int   bj = 0;
#pragma unroll
        for (int q = 0; q < 4; ++q) {
            const f32x2 dx = X[q] - vcx;
            const f32x2 dy = Y[q] - vcy;
            const f32x2 dz = Z[q] - vcz;
            const f32x2 d  = (dx * dx + dy * dy) + dz * dz;  // (xx+yy)+zz, RN
            f32x2 m;
            m.x = fminf(MD[q].x, d.x);
            m.y = fminf(MD[q].y, d.y);
            MD[q] = m;
            // .x is the smaller index -- evaluate first; strict > keeps first max
            const bool g0 = m.x > bm;  bj = g0 ? (2 * q)     : bj;  bm = g0 ? m.x : bm;
            const bool g1 = m.y > bm;  bj = g1 ? (2 * q + 1) : bj;  bm = g1 ? m.y : bm;
        }
        const uint32_t p = (uint32_t)(blk * kPtsPerBlock + bj * kThreads + tid);
        uint64_t pk = ((uint64_t)t << 49) |
                      ((uint64_t)__float_as_uint(bm) << 17) |
                      ((~p) & 0x1FFFFu);

        // --- wave max -> lane 63 -> LDS atomic max (tag-packed, parity dbuf) ---
        pk = wave_max_to_lane63(pk);
        if (lane == 63) {
            __hip_atomic_fetch_max(&lbest[t & 1], pk, __ATOMIC_RELAXED,
                                   __HIP_MEMORY_SCOPE_WORKGROUP);
        }
        __syncthreads();  // the one barrier: block best complete in LDS

        const size_t sbOff = ((size_t)(t & 1) * kB + b) * kBlocksPerBatch;
        uint64_t* const fslot = fastbuf + sbOff;
        uint64_t* const aslot = agentbuf + sbOff;
        if (tid == 0) {
            const uint64_t bv = lbest[t & 1];  // already tagged with t
            st_u64_plain(&fslot[blk], bv);     // fast path: home-XCD L2
            st_u64_agent(&aslot[blk], bv);     // proven path: MALL, any placement
        }

        // --- every wave spins: lanes 0-15, fast phase then agent fallback ---
        const bool wasFast = (fastOK != 0);  // benign race: monotone 1->0
        uint64_t got = 0;
        bool need = lane < kBlocksPerBatch;
        int iter = wasFast ? 0 : kFastIters;
        const uint64_t tt = (uint64_t)t;
        while (__any(need)) {
            if (need) {
                const uint64_t sv = (iter < kFastIters) ? ld_u64_l2(&fslot[lane])
                                                        : ld_u64_agent(&aslot[lane]);
                if ((sv >> 49) == tt) { got = sv; need = false; }
            }
            ++iter;
        }
        if (wasFast && iter > kFastIters && lane == 0) fastOK = 0;  // sticky disable

        got = group16_max(got);  // lanes 0-15 now hold the batch winner

        // broadcast via scalar regs; winner coords from read-only xyz (cached)
        const uint32_t lo = (uint32_t)got;
        const uint32_t widx = 131071u - (__builtin_amdgcn_readfirstlane((int)lo) & 0x1FFFFu);
        cx = base[3 * (size_t)widx + 0];
        cy = base[3 * (size_t)widx + 1];
        cz = base[3 * (size_t)widx + 2];
        if (blk == 0 && tid == 0) {
            float* o = out + ((size_t)b * kNpoint + t) * 3;
            o[0] = cx; o[1] = cy; o[2] = cz;
        }
    }
}

extern "C" void kernel_launch(void* const* d_in, const int* in_sizes, int n_in,
                              void* d_out, int out_size, void* d_ws, size_t ws_size,
                              hipStream_t stream) {
    const float* xyz = (const float*)d_in[0];
    float* out = (float*)d_out;
    uint64_t* ws = (uint64_t*)d_ws;  // fastbuf 2 KiB + agentbuf 2 KiB = 4 KiB
    fps_kernel<<<dim3(kB * kBlocksPerBatch), dim3(kThreads), 0, stream>>>(xyz, out, ws);
}

// Round 5
// 2085.460 us; speedup vs baseline: 1.2390x; 1.0002x over previous
//
#include <hip/hip_runtime.h>
#include <cstdint>

// FPS: B=8, N=131072, NPOINT=1024.  Exact-index replication of the jax reference.
//
// v5: dual-path exchange, skew-robust engagement.
//   * Protocol core (proven v0): 16 blocks/batch, 1024 thr, one barrier/round,
//     LDS atomic-max fan-in, monotone tag-packed keys, parity dbuf, no resets.
//   * tid0 posts the block winner TWICE: plain store -> fastbuf (write-through
//     vL1 -> home-XCD L2; all 16 blocks of a batch land on one XCD under
//     round-robin dispatch b = blockIdx&7) and agent-scope store -> agentbuf
//     (MALL; correct on ANY placement).
//   * fastbuf slots padded to 128 B (one L2 line per poster) so the 16 plain
//     stores never serialize on shared lines.  agentbuf keeps v0's layout.
//   * Pollers (lanes 0-15 of every wave): each lane tries kFastIters sc0
//     (L1-bypass, L2-served) polls of its fast slot, then falls back to its
//     agent slot -- per-lane bounded progress, no hang on any placement.
//   * Sticky disable of the fast phase is only evaluated at t>=2 (round-1
//     startup skew must not poison the verdict -- that was v4's bug: it
//     disabled fast in round 1 and silently ran v0 forever).
// Packed key u64: [t:15][fp32 dist bits:32][(~idx)&0x1FFFF:17] -> unsigned max
// == (round, dist desc, idx asc) == np.argmax first-max tie-break.  Poisoned
// workspace (0x5555...) has tag 0x2AAA > 1023: never matches a live round.

constexpr int kB = 8;
constexpr int kN = 131072;
constexpr int kNpoint = 1024;
constexpr int kBlocksPerBatch = 16;
constexpr int kThreads = 1024;
constexpr int kPPT = 8;
constexpr int kPtsPerBlock = kThreads * kPPT;  // 8192
constexpr int kFastIters = 20;   // per-lane fast-poll budget per round
constexpr int kPad = 16;         // u64 per fast slot = 128 B = one L2 line

typedef float f32x2 __attribute__((ext_vector_type(2)));

__device__ __forceinline__ uint64_t u64max(uint64_t a, uint64_t b) {
    return a > b ? a : b;
}

// DPP move of a u64 (both halves, same ctrl); invalid source lanes yield 0,
// the identity for our non-negative packed keys.
template <int CTRL>
__device__ __forceinline__ uint64_t dpp_u64(uint64_t v) {
    int lo = __builtin_amdgcn_update_dpp(0, (int)(uint32_t)v, CTRL, 0xF, 0xF, false);
    int hi = __builtin_amdgcn_update_dpp(0, (int)(uint32_t)(v >> 32), CTRL, 0xF, 0xF, false);
    return ((uint64_t)(uint32_t)hi << 32) | (uint32_t)lo;
}

// Full-wave max; result valid in lane 63 (row_shr/row_bcast ladder).
__device__ __forceinline__ uint64_t wave_max_to_lane63(uint64_t v) {
    v = u64max(v, dpp_u64<0x111>(v));  // row_shr:1
    v = u64max(v, dpp_u64<0x112>(v));  // row_shr:2
    v = u64max(v, dpp_u64<0x114>(v));  // row_shr:4
    v = u64max(v, dpp_u64<0x118>(v));  // row_shr:8
    v = u64max(v, dpp_u64<0x142>(v));  // row_bcast:15
    v = u64max(v, dpp_u64<0x143>(v));  // row_bcast:31
    return v;
}

// Max over each aligned group of 16 lanes (butterfly xor1,2,4,8).
__device__ __forceinline__ uint64_t group16_max(uint64_t v) {
    v = u64max(v, dpp_u64<0xB1>(v));   // quad_perm xor1
    v = u64max(v, dpp_u64<0x4E>(v));   // quad_perm xor2
    v = u64max(v, dpp_u64<0x141>(v));  // row_half_mirror
    v = u64max(v, dpp_u64<0x140>(v));  // row_mirror
    return v;
}

__device__ __forceinline__ uint64_t ld_u64_agent(const uint64_t* p) {
    return __hip_atomic_load(p, __ATOMIC_RELAXED, __HIP_MEMORY_SCOPE_AGENT);
}
__device__ __forceinline__ void st_u64_agent(uint64_t* p, uint64_t v) {
    __hip_atomic_store(p, v, __ATOMIC_RELAXED, __HIP_MEMORY_SCOPE_AGENT);
}
// Plain store: vL1 is write-through -> lands in the home XCD's L2.
__device__ __forceinline__ void st_u64_plain(uint64_t* p, uint64_t v) {
    asm volatile("global_store_dwordx2 %0, %1, off" :: "v"(p), "v"(v) : "memory");
}
// SE-scope load (bypass L1, read L2). Load + waitcnt fused in ONE asm so the
// dependent tag check cannot be scheduled before the wait (rule #18).
__device__ __forceinline__ uint64_t ld_u64_l2(const uint64_t* p) {
    uint64_t v;
    asm volatile("global_load_dwordx2 %0, %1, off sc0\n\t"
                 "s_waitcnt vmcnt(0)"
                 : "=v"(v) : "v"(p) : "memory");
    return v;
}

__global__ __launch_bounds__(kThreads, 4) void fps_kernel(
        const float* __restrict__ xyz, float* __restrict__ out,
        uint64_t* __restrict__ ws) {
#pragma clang fp contract(off)
    const int b    = blockIdx.x & 7;    // batch: all 16 blocks of a batch on one XCD
    const int blk  = blockIdx.x >> 3;   // block within batch, 0..15
    const int tid  = threadIdx.x;
    const int lane = tid & 63;

    uint64_t* const fastbuf  = ws;  // [2][8][16][kPad] u64 = 32 KiB
    uint64_t* const agentbuf = ws + 2 * kB * kBlocksPerBatch * kPad;  // [2][8][16]

    const float* __restrict__ base = xyz + (size_t)b * kN * 3;

    // Register-resident state as packed pairs: .x is point j=2q, .y is j=2q+1
    // (ascending index order preserved for the first-max tie-break).
    f32x2 X[4], Y[4], Z[4], MD[4];
#pragma unroll
    for (int q = 0; q < 4; ++q) {
        const int p0 = blk * kPtsPerBlock + (2 * q) * kThreads + tid;
        const int p1 = p0 + kThreads;
        X[q].x = base[3 * p0 + 0]; X[q].y = base[3 * p1 + 0];
        Y[q].x = base[3 * p0 + 1]; Y[q].y = base[3 * p1 + 1];
        Z[q].x = base[3 * p0 + 2]; Z[q].y = base[3 * p1 + 2];
        MD[q].x = __builtin_inff(); MD[q].y = __builtin_inff();
    }

    __shared__ uint64_t lbest[2];
    __shared__ int fastOK;
    if (tid == 0) { lbest[0] = 0; lbest[1] = 0; fastOK = 1; }

    // First sample is always point 0.
    float cx = base[0], cy = base[1], cz = base[2];
    if (blk == 0 && tid == 0) {
        float* o = out + (size_t)b * kNpoint * 3;
        o[0] = cx; o[1] = cy; o[2] = cz;
    }
    __syncthreads();  // lbest/fastOK init visible

    for (int t = 1; t < kNpoint; ++t) {
        // --- mindist update + per-thread argmax (exact fp32, no contraction) ---
        const f32x2 vcx = {cx, cx}, vcy = {cy, cy}, vcz = {cz, cz};
        float bm = -1.0f;
        int   bj = 0;
#pragma unroll
        for (int q = 0; q < 4; ++q) {
            const f32x2 dx = X[q] - vcx;
            const f32x2 dy = Y[q] - vcy;
            const f32x2 dz = Z[q] - vcz;
            const f32x2 d  = (dx * dx + dy * dy) + dz * dz;  // (xx+yy)+zz, RN
            f32x2 m;
            m.x = fminf(MD[q].x, d.x);
            m.y = fminf(MD[q].y, d.y);
            MD[q] = m;
            // .x is the smaller index -- evaluate first; strict > keeps first max
            const bool g0 = m.x > bm;  bj = g0 ? (2 * q)     : bj;  bm = g0 ? m.x : bm;
            const bool g1 = m.y > bm;  bj = g1 ? (2 * q + 1) : bj;  bm = g1 ? m.y : bm;
        }
        const uint32_t p = (uint32_t)(blk * kPtsPerBlock + bj * kThreads + tid);
        uint64_t pk = ((uint64_t)t << 49) |
                      ((uint64_t)__float_as_uint(bm) << 17) |
                      ((~p) & 0x1FFFFu);

        // --- wave max -> lane 63 -> LDS atomic max (tag-packed, parity dbuf) ---
        pk = wave_max_to_lane63(pk);
        if (lane == 63) {
            __hip_atomic_fetch_max(&lbest[t & 1], pk, __ATOMIC_RELAXED,
                                   __HIP_MEMORY_SCOPE_WORKGROUP);
        }
        __syncthreads();  // the one barrier: block best complete in LDS

        uint64_t* const fslot = fastbuf +
                ((size_t)(t & 1) * kB + b) * kBlocksPerBatch * kPad;
        uint64_t* const aslot = agentbuf +
                ((size_t)(t & 1) * kB + b) * kBlocksPerBatch;
        if (tid == 0) {
            const uint64_t bv = lbest[t & 1];       // already tagged with t
            st_u64_plain(&fslot[(size_t)blk * kPad], bv);  // home-XCD L2
            st_u64_agent(&aslot[blk], bv);                 // MALL, any placement
        }

        // --- every wave spins: lanes 0-15; per-lane fast budget then agent ---
        const bool wasFast = (fastOK != 0);  // benign race: monotone 1->0
        uint64_t got = 0;
        bool need = lane < kBlocksPerBatch;
        int fiter = wasFast ? 0 : kFastIters;  // skip fast phase if disabled
        int li = 0;
        const uint64_t tt = (uint64_t)t;
        while (__any(need)) {
            if (need) {
                const uint64_t sv = (fiter < kFastIters)
                        ? ld_u64_l2(&fslot[(size_t)lane * kPad])
                        : ld_u64_agent(&aslot[lane]);
                if ((sv >> 49) == tt) { got = sv; need = false; }
            }
            ++fiter;
            ++li;
        }
        // Disable fast phase only on steady-state evidence (t>=2): round-1
        // startup skew must not poison the verdict (v4's bug).
        if (t >= 2 && wasFast && li > kFastIters && lane == 0) fastOK = 0;

        got = group16_max(got);  // lanes 0-15 now hold the batch winner

        // broadcast via scalar regs; winner coords from read-only xyz (cached)
        const uint32_t lo = (uint32_t)got;
        const uint32_t widx = 131071u - (__builtin_amdgcn_readfirstlane((int)lo) & 0x1FFFFu);
        cx = base[3 * (size_t)widx + 0];
        cy = base[3 * (size_t)widx + 1];
        cz = base[3 * (size_t)widx + 2];
        if (blk == 0 && tid == 0) {
            float* o = out + ((size_t)b * kNpoint + t) * 3;
            o[0] = cx; o[1] = cy; o[2] = cz;
        }
    }
}

extern "C" void kernel_launch(void* const* d_in, const int* in_sizes, int n_in,
                              void* d_out, int out_size, void* d_ws, size_t ws_size,
                              hipStream_t stream) {
    const float* xyz = (const float*)d_in[0];
    float* out = (float*)d_out;
    uint64_t* ws = (uint64_t*)d_ws;  // fastbuf 32 KiB + agentbuf 2 KiB
    fps_kernel<<<dim3(kB * kBlocksPerBatch), dim3(kThreads), 0, stream>>>(xyz, out, ws);
}